// Round 1
// baseline (600.432 us; speedup 1.0000x reference)
//
#include <hip/hip_runtime.h>

typedef _Float16 f16;
typedef _Float16 f16x8 __attribute__((ext_vector_type(8)));
typedef float f32x4 __attribute__((ext_vector_type(4)));
typedef unsigned short u16x8 __attribute__((ext_vector_type(8)));

// async global->LDS, 16B per lane; LDS dest is wave-uniform base + lane*16
static __device__ __forceinline__ void gload16(const void* g, void* l) {
  __builtin_amdgcn_global_load_lds(
      (__attribute__((address_space(1))) unsigned int*)(g),
      (__attribute__((address_space(3))) unsigned int*)(l), 16, 0, 0);
}

// ---------------------------------------------------------------------------
// Kernel 0a: split W (640x512 fp32, row-major [n][k]) into f16 hi/lo planes.
// lo is pre-scaled by 2^11 so it stays in f16 normal range (|w|<=0.0442 ->
// |w_lo_raw| <= 2^-12*0.0442 ~ 1e-5 would be ALL denormal unscaled).
// ---------------------------------------------------------------------------
__global__ void pq_splitw(const float* __restrict__ w,
                          f16* __restrict__ wh, f16* __restrict__ wl) {
  const int i = blockIdx.x * 256 + threadIdx.x;   // grid covers exactly 327680
  const float f = w[i];
  const f16 h = (f16)f;
  wh[i] = h;
  wl[i] = (f16)((f - (float)h) * 2048.0f);
}

// ---------------------------------------------------------------------------
// Kernel 0b: x (B,512,4096) fp32 -> Xhi/Xlo f16 planes in [b][t][k] layout
// (transposed), via a 64k x 64t LDS tile. lo pre-scaled by 2^11.
// ---------------------------------------------------------------------------
__global__ void pq_splitx(const float* __restrict__ x,
                          f16* __restrict__ Xh, f16* __restrict__ Xl) {
  __shared__ __align__(16) float sT[64 * 68];   // pad 64->68 (16B-aligned rows)
  const int tid = threadIdx.x;
  const int bid = blockIdx.x;                   // tt + 64*(kt + 8*b)
  const int tt = bid & 63;
  const int kt = (bid >> 6) & 7;
  const int b  = bid >> 9;
  const long xbase = ((long)(b * 512 + kt * 64)) * 4096 + tt * 64;
  const int t4 = tid & 15;        // float4 slot along t
  const int kr = tid >> 4;        // k row 0..15 (+16 per iter)
#pragma unroll
  for (int it = 0; it < 4; ++it) {
    const int k = it * 16 + kr;
    const float4 v = *(const float4*)(x + xbase + (long)k * 4096 + t4 * 4);
    *(float4*)(sT + k * 68 + t4 * 4) = v;
  }
  __syncthreads();
  const int t  = tid >> 2;        // 0..63
  const int kg = tid & 3;         // 16-k group
  u16x8 h0, h1, l0, l1;
#pragma unroll
  for (int j = 0; j < 16; ++j) {
    const float f = sT[(kg * 16 + j) * 68 + t];
    const f16 hh = (f16)f;
    const f16 ll = (f16)((f - (float)hh) * 2048.0f);
    const unsigned short hu = __builtin_bit_cast(unsigned short, hh);
    const unsigned short lu = __builtin_bit_cast(unsigned short, ll);
    if (j < 8) { h0[j] = hu; l0[j] = lu; }
    else       { h1[j - 8] = hu; l1[j - 8] = lu; }
  }
  const long ob = ((long)(b * 4096 + tt * 64 + t)) * 512 + kt * 64 + kg * 16;
  *(u16x8*)(Xh + ob)     = h0;
  *(u16x8*)(Xh + ob + 8) = h1;
  *(u16x8*)(Xl + ob)     = l0;
  *(u16x8*)(Xl + ob + 8) = l1;
}

// ---------------------------------------------------------------------------
// Kernel 1: logits = xt @ W^T + b via 16x16x32 f16 MFMA, 3-product f16 split.
//   logit = sum xhi*whi  +  2^-11 * (sum xlo'*whi + xhi*wlo')
// Tile 128t x 128n, BK=64, 4 waves (2x2), each wave 64x64 (4x4 frags).
// Staging: each wave global_load_lds's one 16KB plane; 16B-block XOR swizzle
// (slot ^ (row&7)) applied on the GLOBAL source (LDS dest linear, rule #21),
// same involution applied on the ds_read side -> conflict-free-ish b128 reads.
// ---------------------------------------------------------------------------
__global__ __launch_bounds__(256, 2) void pq_gemm(
    const f16* __restrict__ Xh, const f16* __restrict__ Xl,
    const f16* __restrict__ Wh, const f16* __restrict__ Wl,
    const float* __restrict__ bias, float* __restrict__ out0) {
  __shared__ __align__(16) f16 sXh[128 * 64];
  __shared__ __align__(16) f16 sXl[128 * 64];
  __shared__ __align__(16) f16 sWh[128 * 64];
  __shared__ __align__(16) f16 sWl[128 * 64];

  const int tid  = threadIdx.x;
  const int lane = tid & 63;
  const int w    = __builtin_amdgcn_readfirstlane(tid >> 6);

  // bijective XCD swizzle: grid 2560 = 8 XCD * 320
  const int orig = blockIdx.x;
  const int wid  = (orig & 7) * 320 + (orig >> 3);
  const int nt = wid % 5;          // n-tile fastest -> x-tile L2 reuse per XCD
  const int tt = (wid / 5) & 31;
  const int b  = wid / 160;
  const int t0 = tt * 128;
  const int n0 = nt * 128;

  // ---- staging setup: wave w owns plane w ----
  const f16* gplane = (w == 0) ? Xh : (w == 1) ? Xl : (w == 2) ? Wh : Wl;
  f16* splane       = (w == 0) ? sXh : (w == 1) ? sXl : (w == 2) ? sWh : sWl;
  const long rowg0  = (w < 2) ? (long)(b * 4096 + t0) : (long)n0;
  const int srow = lane >> 3;                  // row-in-8 (tile row = j*8+srow)
  const int slot = lane & 7;                   // 16B slot within 128B row
  const int kb   = slot ^ (srow & 7);          // inverse-swizzled global k-block
  const f16* gsrc0 = gplane + (rowg0 + srow) * 512 + kb * 8;

  f32x4 acc1[4][4] = {};
  f32x4 acc2[4][4] = {};

  const int wm = w & 1;
  const int wn = w >> 1;
  const int lm = lane & 15;        // frag row (t or n)
  const int lk = lane >> 4;        // k group
  const int rl7 = lm & 7;          // (row & 7) for read-side swizzle

  for (int kc = 0; kc < 8; ++kc) {
    const f16* g = gsrc0 + kc * 64;
#pragma unroll
    for (int j = 0; j < 16; ++j)
      gload16(g + (long)j * 8 * 512, splane + j * 512);
    __syncthreads();   // drains vmcnt(0): staged data visible

#pragma unroll
    for (int ks = 0; ks < 2; ++ks) {
      const int ko = ((ks * 4 + lk) ^ rl7) * 8;
      f16x8 ah[4], al[4];
#pragma unroll
      for (int mf = 0; mf < 4; ++mf) {
        const int ro = (wm * 64 + mf * 16 + lm) * 64 + ko;
        ah[mf] = *(const f16x8*)(sXh + ro);
        al[mf] = *(const f16x8*)(sXl + ro);
      }
#pragma unroll
      for (int nf = 0; nf < 4; ++nf) {
        const int ro = (wn * 64 + nf * 16 + lm) * 64 + ko;
        const f16x8 bh = *(const f16x8*)(sWh + ro);
        const f16x8 bl = *(const f16x8*)(sWl + ro);
#pragma unroll
        for (int mf = 0; mf < 4; ++mf) {
          acc1[mf][nf] = __builtin_amdgcn_mfma_f32_16x16x32_f16(ah[mf], bh, acc1[mf][nf], 0, 0, 0);
          acc2[mf][nf] = __builtin_amdgcn_mfma_f32_16x16x32_f16(al[mf], bh, acc2[mf][nf], 0, 0, 0);
          acc2[mf][nf] = __builtin_amdgcn_mfma_f32_16x16x32_f16(ah[mf], bl, acc2[mf][nf], 0, 0, 0);
        }
      }
    }
    __syncthreads();   // LDS reuse barrier before next stage
  }

  // epilogue: combine split accumulators, add bias, store fp32 logits
#pragma unroll
  for (int nf = 0; nf < 4; ++nf) {
    const int ng = n0 + wn * 64 + nf * 16 + lm;
    const float bv = bias[ng];
#pragma unroll
    for (int mf = 0; mf < 4; ++mf) {
      const int tg = t0 + wm * 64 + mf * 16 + lk * 4;
#pragma unroll
      for (int r = 0; r < 4; ++r) {
        const float v = acc1[mf][nf][r] + acc2[mf][nf][r] * (1.0f / 2048.0f) + bv;
        out0[((long)(b * 4096 + tg + r)) * 640 + ng] = v;
      }
    }
  }
}

// ---------------------------------------------------------------------------
// Kernel 2: per (b,t): argmax over (logits+gumbel) per group (tau=1), then
// q[b,t,g*128:...] = codevectors[g, idx, :] (exact fp32 copy; forward value
// of the straight-through hard one-hot). First-index tie-break == np.argmax.
// One wave per row, 4 rows/block.
// ---------------------------------------------------------------------------
__global__ void pq_argmax(const float* __restrict__ logits,
                          const float* __restrict__ gum,
                          const float* __restrict__ cv,
                          float* __restrict__ q) {
  const int tid = threadIdx.x;
  const int lane = tid & 63;
  const int row = blockIdx.x * 4 + (tid >> 6);     // b*T + t
  const float* lg = logits + (long)row * 640;
  const float* gn = gum + (long)row * 640;
#pragma unroll
  for (int g = 0; g < 2; ++g) {
    float bv = -3.4e38f;
    int bi = 0;
#pragma unroll
    for (int i = 0; i < 5; ++i) {
      const int e = i * 64 + lane;                 // ascending -> keep-first
      const int o = g * 320 + e;
      const float v = lg[o] + gn[o];
      if (v > bv) { bv = v; bi = e; }
    }
#pragma unroll
    for (int off = 32; off; off >>= 1) {
      const float ov = __shfl_xor(bv, off, 64);
      const int oi = __shfl_xor(bi, off, 64);
      if (ov > bv || (ov == bv && oi < bi)) { bv = ov; bi = oi; }
    }
    const float2 cvv = *(const float2*)(cv + ((long)(g * 320 + bi)) * 128 + lane * 2);
    *(float2*)(q + (long)row * 256 + g * 128 + lane * 2) = cvv;
  }
}

// ---------------------------------------------------------------------------
extern "C" void kernel_launch(void* const* d_in, const int* in_sizes, int n_in,
                              void* d_out, int out_size, void* d_ws, size_t ws_size,
                              hipStream_t stream) {
  const float* x  = (const float*)d_in[0];   // (16, 512, 4096)
  const float* gn = (const float*)d_in[1];   // (16, 4096, 2, 320)
  const float* pw = (const float*)d_in[2];   // (640, 512)
  const float* pb = (const float*)d_in[3];   // (640,)
  const float* cv = (const float*)d_in[4];   // (1, 640, 128)

  float* logits = (float*)d_out;             // 16*4096*640 = 41,943,040
  float* q = (float*)d_out + 41943040L;      // 16*4096*256 = 16,777,216

  // workspace layout (needs ~135.6 MB)
  char* ws = (char*)d_ws;
  f16* Xh = (f16*)(ws);
  f16* Xl = (f16*)(ws + 67108864L);
  f16* Wh = (f16*)(ws + 134217728L);
  f16* Wl = (f16*)(ws + 134217728L + 655360L);

  pq_splitw<<<dim3(1280), dim3(256), 0, stream>>>(pw, Wh, Wl);
  pq_splitx<<<dim3(8192), dim3(256), 0, stream>>>(x, Xh, Xl);
  pq_gemm<<<dim3(2560), dim3(256), 0, stream>>>(Xh, Xl, Wh, Wl, pb, logits);
  pq_argmax<<<dim3(16384), dim3(256), 0, stream>>>(logits, gn, cv, q);
}